// Round 1
// baseline (118.861 us; speedup 1.0000x reference)
//
#include <hip/hip_runtime.h>
#include <cstdint>

// Problem constants (static shapes from setup_inputs):
//   LEVEL_SIZES = {256,128,64,32,16}, B=16, N=64 boxes, C=8, img 1024x1024
#define NBOX 64
#define NB   16
#define NC   8

// ws layout:
//   [0      .. 7680)   float acc[5][16][8][3]   (bce_sum, p_sum, pt_sum) -- memset 0
//   [7680   .. 8000)   float tcnt[5][16]        (written directly, no zero needed)
//   [8192   .. 186368) u64 mask words: per level base (words) {0,16384,20480,21504,22016}
//                      level l: 16 images x Hl rows x W64 words

__device__ __forceinline__ unsigned long long range_mask(int a, int e, int base) {
    int lo = a - base; lo = lo < 0 ? 0 : (lo > 64 ? 64 : lo);
    int hi = e - base; hi = hi < 0 ? 0 : (hi > 64 ? 64 : hi);
    if (hi <= lo) return 0ULL;
    unsigned long long hm = (hi >= 64) ? ~0ULL : ((1ULL << hi) - 1ULL);
    unsigned long long lm = (1ULL << lo) - 1ULL;   // lo in [0,63] here
    return hm & ~lm;
}

__global__ __launch_bounds__(256)
void k_mask(const float* __restrict__ bboxs,
            const int* __restrict__ ih_p, const int* __restrict__ iw_p,
            const int* __restrict__ alpha_p, const int* __restrict__ beta_p,
            unsigned long long* __restrict__ mask,
            float* __restrict__ tcnt) {
    const int bid = blockIdx.x;            // 80 blocks = 16 images x 5 levels
    const int l = bid % 5, b = bid / 5;
    const int Hl = 256 >> l;               // Hl == Wl
    const int W64 = (Hl >= 64) ? (Hl >> 6) : 1;
    const int mb_[5] = {0, 16384, 20480, 21504, 22016};
    const int mbase = mb_[l] + b * Hl * W64;

    const float w = (float)iw_p[0], h = (float)ih_p[0];
    const int alpha = alpha_p[0], beta = beta_p[0];
    const float side = (float)(1 << (l + alpha));
    const float min_a = side * side;
    const float sb = side * (float)beta;
    const float max_a = sb * sb;
    const float sx = (float)Hl / w;
    const float sy = (float)Hl / h;

    __shared__ int rx1[NBOX], rx2[NBOX], ry1[NBOX], ry2[NBOX];
    const int tid = threadIdx.x;
    if (tid < NBOX) {
        const float* bb = bboxs + (size_t)(b * NBOX + tid) * 4;
        float x1 = bb[0], y1 = bb[1], x2 = bb[2], y2 = bb[3];
        bool valid = (x1 <= w) && (y1 <= h) && (x2 <= w) && (y2 <= h);
        float area = fabsf((x2 - x1) * (y2 - y1));
        bool sel = valid && (area >= min_a) && (area <= max_a);
        int xi1 = (int)fmaxf(floorf(x1 * sx), 0.f);
        int yi1 = (int)fmaxf(floorf(y1 * sy), 0.f);
        int xi2 = (int)fminf(ceilf(x2 * sx) + 1.f, (float)Hl);
        int yi2 = (int)fminf(ceilf(y2 * sy) + 1.f, (float)Hl);
        rx1[tid] = xi1; rx2[tid] = xi2;
        ry1[tid] = sel ? yi1 : 0;
        ry2[tid] = sel ? yi2 : 0;    // empty y-range when not selected
    }
    __syncthreads();

    int myt = 0;
    for (int hh = tid; hh < Hl; hh += 256) {
        unsigned long long m0 = 0, m1 = 0, m2 = 0, m3 = 0;
        for (int n = 0; n < NBOX; ++n) {
            if (hh >= ry1[n] && hh < ry2[n]) {
                int a = rx1[n], e = rx2[n];
                m0 |= range_mask(a, e, 0);
                m1 |= range_mask(a, e, 64);
                m2 |= range_mask(a, e, 128);
                m3 |= range_mask(a, e, 192);
            }
        }
        unsigned long long* dst = mask + mbase + hh * W64;
        dst[0] = m0;              myt += __popcll(m0);
        if (W64 > 1) { dst[1] = m1; myt += __popcll(m1); }
        if (W64 > 2) { dst[2] = m2; myt += __popcll(m2);
                       dst[3] = m3; myt += __popcll(m3); }
    }

    // block reduce myt (4 waves of 64)
    for (int off = 32; off > 0; off >>= 1) myt += __shfl_down(myt, off, 64);
    __shared__ int red[4];
    if ((tid & 63) == 0) red[tid >> 6] = myt;
    __syncthreads();
    if (tid == 0)
        tcnt[l * NB + b] = (float)(red[0] + red[1] + red[2] + red[3]);
}

__global__ __launch_bounds__(256)
void k_sums(const float* __restrict__ a0, const float* __restrict__ a1,
            const float* __restrict__ a2, const float* __restrict__ a3,
            const float* __restrict__ a4,
            const unsigned long long* __restrict__ mask,
            float* __restrict__ acc) {
    const int bid = blockIdx.x;
    int l, rel;
    if      (bid < 1024) { l = 0; rel = bid; }
    else if (bid < 1280) { l = 1; rel = bid - 1024; }
    else if (bid < 1408) { l = 2; rel = bid - 1280; }
    else if (bid < 1536) { l = 3; rel = bid - 1408; }
    else                 { l = 4; rel = bid - 1536; }
    const int ntl[5] = {8, 2, 1, 1, 1};
    const int mb_[5] = {0, 16384, 20480, 21504, 22016};
    const int nt = ntl[l];
    const int tile = rel % nt;
    const int bc = rel / nt;
    const int c = bc & 7, b = bc >> 3;
    const int Hl = 256 >> l;
    const int P  = Hl * Hl;
    const int logW = 8 - l;
    const int W64 = (Hl >= 64) ? (Hl >> 6) : 1;

    const float* attn = (l == 0) ? a0 : (l == 1) ? a1 : (l == 2) ? a2 : (l == 3) ? a3 : a4;
    const float* p = attn + (size_t)(b * NC + c) * P;
    const unsigned long long* mrow = mask + mb_[l] + b * Hl * W64;

    const int start = tile * 8192;
    const int end = min(start + 8192, P);

    float bce = 0.f, ps = 0.f, pts = 0.f;
    const int tid = threadIdx.x;
    for (int i = start + tid * 4; i < end; i += 1024) {
        float4 v = *(const float4*)(p + i);
        int hh = i >> logW;
        int ww = i & (Hl - 1);
        unsigned long long wd = mrow[hh * W64 + (ww >> 6)];
        unsigned int bits = (unsigned int)(wd >> (ww & 63)) & 0xFu;
        { float pv = v.x; bool t = bits & 1u; bce -= __logf(t ? pv : 1.f - pv); ps += pv; if (t) pts += pv; }
        { float pv = v.y; bool t = bits & 2u; bce -= __logf(t ? pv : 1.f - pv); ps += pv; if (t) pts += pv; }
        { float pv = v.z; bool t = bits & 4u; bce -= __logf(t ? pv : 1.f - pv); ps += pv; if (t) pts += pv; }
        { float pv = v.w; bool t = bits & 8u; bce -= __logf(t ? pv : 1.f - pv); ps += pv; if (t) pts += pv; }
    }

    for (int off = 32; off > 0; off >>= 1) {
        bce += __shfl_down(bce, off, 64);
        ps  += __shfl_down(ps,  off, 64);
        pts += __shfl_down(pts, off, 64);
    }
    __shared__ float red[4][3];
    if ((tid & 63) == 0) {
        int wv = tid >> 6;
        red[wv][0] = bce; red[wv][1] = ps; red[wv][2] = pts;
    }
    __syncthreads();
    if (tid == 0) {
        float rb = red[0][0] + red[1][0] + red[2][0] + red[3][0];
        float rp = red[0][1] + red[1][1] + red[2][1] + red[3][1];
        float rt = red[0][2] + red[1][2] + red[2][2] + red[3][2];
        float* dst = acc + ((size_t)(l * NB + b) * NC + c) * 3;
        atomicAdd(dst + 0, rb);
        atomicAdd(dst + 1, rp);
        atomicAdd(dst + 2, rt);
    }
}

__global__ void k_final(const float* __restrict__ acc, const float* __restrict__ tcnt,
                        const float* __restrict__ bboxs,
                        const int* __restrict__ ih_p, const int* __restrict__ iw_p,
                        float* __restrict__ out) {
    const int tid = threadIdx.x;   // 64 threads
    __shared__ float per_img[NB];
    const float w = (float)iw_p[0], h = (float)ih_p[0];
    if (tid < NB) {
        const int b = tid;
        float s = 0.f;
        for (int l = 0; l < 5; ++l) {
            int Hl = 256 >> l;
            float invP = 1.f / (float)(Hl * Hl);
            float tc = tcnt[l * NB + b];
            for (int c = 0; c < NC; ++c) {
                const float* a = acc + ((size_t)(l * NB + b) * NC + c) * 3;
                float bce = a[0] * invP;
                float inter = 2.f * a[2] + 1e-8f;
                float uni = a[1] + tc + 1e-8f;
                float dice = 1.f - inter / uni;
                s += 0.5f * bce + 0.5f * dice;
            }
        }
        s *= (1.f / 40.f);   // mean over 5 levels x 8 channels
        bool has = false;
        const float* bb = bboxs + (size_t)b * NBOX * 4;
        for (int n = 0; n < NBOX; ++n) {
            float x1 = bb[n * 4 + 0], y1 = bb[n * 4 + 1];
            float x2 = bb[n * 4 + 2], y2 = bb[n * 4 + 3];
            if (x1 <= w && y1 <= h && x2 <= w && y2 <= h) { has = true; break; }
        }
        per_img[b] = has ? s : 0.f;
    }
    __syncthreads();
    if (tid == 0) {
        float t = 0.f;
        for (int i = 0; i < NB; ++i) t += per_img[i];
        out[0] = t * (1.f / (float)NB);
    }
}

extern "C" void kernel_launch(void* const* d_in, const int* in_sizes, int n_in,
                              void* d_out, int out_size, void* d_ws, size_t ws_size,
                              hipStream_t stream) {
    const float* a0 = (const float*)d_in[0];
    const float* a1 = (const float*)d_in[1];
    const float* a2 = (const float*)d_in[2];
    const float* a3 = (const float*)d_in[3];
    const float* a4 = (const float*)d_in[4];
    const float* bboxs = (const float*)d_in[5];
    const int* ih = (const int*)d_in[6];
    const int* iw = (const int*)d_in[7];
    const int* al = (const int*)d_in[8];
    const int* be = (const int*)d_in[9];

    float* acc = (float*)d_ws;                                   // 1920 floats
    float* tcnt = acc + 1920;                                    // 80 floats
    unsigned long long* mask = (unsigned long long*)((char*)d_ws + 8192);

    hipMemsetAsync(d_ws, 0, 1920 * sizeof(float), stream);       // zero accumulators
    k_mask<<<80, 256, 0, stream>>>(bboxs, ih, iw, al, be, mask, tcnt);
    k_sums<<<1664, 256, 0, stream>>>(a0, a1, a2, a3, a4, mask, acc);
    k_final<<<1, 64, 0, stream>>>(acc, tcnt, bboxs, ih, iw, (float*)d_out);
}